// Round 9
// baseline (1453.826 us; speedup 1.0000x reference)
//
#include <hip/hip_runtime.h>
#include <hip/hip_bf16.h>

// Problem constants: D=1024, N=4096, K=16, M = N*K = 65536, K-dim main = 2048

typedef __attribute__((ext_vector_type(4))) float f32x4;
typedef __attribute__((ext_vector_type(8))) short bf16x8;

__device__ __forceinline__ ushort f2bf(float f) {
  unsigned b = __builtin_bit_cast(unsigned, f);
  b += 0x7FFFu + ((b >> 16) & 1u);   // RNE
  return (ushort)(b >> 16);
}
__device__ __forceinline__ unsigned pk2(float a, float b) {
  return (unsigned)f2bf(a) | ((unsigned)f2bf(b) << 16);
}

// LDS XOR swizzle for the A tile (verified in passing R1/R4/R6/R7/R8 kernels)
__device__ __forceinline__ unsigned swz(unsigned a) {
  return a ^ (((a >> 7) & 3u) << 4);
}

__device__ __forceinline__ bf16x8 cvt8(const float* p) {
  f32x4 a = *(const f32x4*)p;
  f32x4 b = *(const f32x4*)(p + 4);
  bf16x8 r;
  r[0] = (short)f2bf(a[0]); r[1] = (short)f2bf(a[1]);
  r[2] = (short)f2bf(a[2]); r[3] = (short)f2bf(a[3]);
  r[4] = (short)f2bf(b[0]); r[5] = (short)f2bf(b[1]);
  r[6] = (short)f2bf(b[2]); r[7] = (short)f2bf(b[3]);
  return r;
}

// ---------------------------------------------------------------------------
// prep: LDS tile-transpose weight packer (verified green R4-R8).
// mode 0 (bid<512):  Bmain packed layout: flat = kt*32768 + wg*4096 + c*8 + m,
//                    chunk c = nf*64 + lane; value = Wl[1024+kt*32+(lane>>4)*8+m]
//                                                      [wg*128+nf*16+(lane&15)]
// mode 1 (512..768): Bk1 layout [kt][nn][q*8+m] from Wl rows 0..1023
// mode 2 (768..1280): Bgate same layout from Wg rows kt*32 (+ row+1024 summed
//                    when kt>=32)
// ---------------------------------------------------------------------------
__global__ __launch_bounds__(256) void prep_kernel(
    const float* __restrict__ Wl, const float* __restrict__ Wg,
    ushort* __restrict__ Bmain, ushort* __restrict__ Bk1,
    ushort* __restrict__ Bgate) {
  __shared__ float L[32][129];
  int t = threadIdx.x;
  int bid = blockIdx.x;
  const float* src; int row0, mode, kt, wg; ushort* dst;
  if (bid < 512)      { mode = 0; kt = bid >> 3;        wg = bid & 7; src = Wl; row0 = 1024 + kt * 32; dst = Bmain; }
  else if (bid < 768) { mode = 1; kt = (bid - 512) >> 3; wg = (bid - 512) & 7; src = Wl; row0 = kt * 32; dst = Bk1; }
  else                { mode = 2; kt = (bid - 768) >> 3; wg = (bid - 768) & 7; src = Wg; row0 = kt * 32; dst = Bgate; }
  int col0 = wg * 128;
  bool dosum = (mode == 2) && (kt >= 32);
#pragma unroll
  for (int p = 0; p < 4; ++p) {
    int r = p * 8 + (t >> 5), c = (t & 31) * 4;
    const float* sp = src + (size_t)(row0 + r) * 1024 + col0 + c;
    f32x4 v = *(const f32x4*)sp;
    if (dosum) { f32x4 v2 = *(const f32x4*)(sp + (size_t)1024 * 1024); v += v2; }
    L[r][c] = v[0]; L[r][c + 1] = v[1]; L[r][c + 2] = v[2]; L[r][c + 3] = v[3];
  }
  __syncthreads();
  if (mode == 0) {
    for (int c = t; c < 512; c += 256) {
      int nf = c >> 6, lane = c & 63, lr_ = lane & 15, lh_ = lane >> 4;
      bf16x8 o;
#pragma unroll
      for (int m = 0; m < 8; ++m) o[m] = (short)f2bf(L[lh_ * 8 + m][nf * 16 + lr_]);
      *(bf16x8*)(dst + (size_t)kt * 32768 + wg * 4096 + c * 8) = o;
    }
  } else {
    for (int c = t; c < 512; c += 256) {
      int nn = c >> 2, q = c & 3;
      bf16x8 o;
#pragma unroll
      for (int m = 0; m < 8; ++m) o[m] = (short)f2bf(L[q * 8 + m][nn]);
      *(bf16x8*)(dst + (size_t)kt * 32768 + (size_t)(wg * 128 + nn) * 32 + q * 8) = o;
    }
  }
}

// ---------------------------------------------------------------------------
// gemm_small: C = act(A_f32 @ Bpack + bias). 64x128 tile, 4 waves (2x2),
// wave tile 32x64. grid (M/64, 8) = 512 blocks -> 2 blocks/CU. (green)
// ---------------------------------------------------------------------------
template <int NKT, int NSPLIT, int ACT>
__global__ __launch_bounds__(256) void gemm_small(
    const float* __restrict__ A0, const float* __restrict__ A1,
    const ushort* __restrict__ Bp, const float* __restrict__ bias,
    float* __restrict__ Cout) {
  int tid = threadIdx.x, l = tid & 63, wid = tid >> 6;
  int wm = wid & 1, wn = wid >> 1;
  int mbase = blockIdx.x * 64 + wm * 32;
  int nbase = blockIdx.y * 128 + wn * 64;
  int lr = l & 15, lh = l >> 4;
  f32x4 acc[2][4] = {};
#pragma unroll 1
  for (int kt = 0; kt < NKT; ++kt) {
    const float* As = (kt < NSPLIT) ? A0 : A1;
    int ke = ((kt < NSPLIT) ? kt : kt - NSPLIT) * 32 + lh * 8;
    bf16x8 af[2];
#pragma unroll
    for (int mf = 0; mf < 2; ++mf)
      af[mf] = cvt8(As + (size_t)(mbase + mf * 16 + lr) * 1024 + ke);
    bf16x8 bf[4];
#pragma unroll
    for (int nf = 0; nf < 4; ++nf)
      bf[nf] = *(const bf16x8*)(Bp + (size_t)kt * 32768 +
                                (size_t)(nbase + nf * 16 + lr) * 32 + lh * 8);
#pragma unroll
    for (int nf = 0; nf < 4; ++nf)
#pragma unroll
      for (int mf = 0; mf < 2; ++mf)
        acc[mf][nf] = __builtin_amdgcn_mfma_f32_16x16x32_bf16(
            af[mf], bf[nf], acc[mf][nf], 0, 0, 0);
  }
#pragma unroll
  for (int nf = 0; nf < 4; ++nf) {
    int col = nbase + nf * 16 + lr;
    float bs = bias[col];
#pragma unroll
    for (int mf = 0; mf < 2; ++mf)
#pragma unroll
      for (int j = 0; j < 4; ++j) {
        int row = mbase + mf * 16 + lh * 4 + j;
        float v = acc[mf][nf][j] + bs;
        if (ACT == 1) v = 1.0f / (1.0f + expf(-v));
        Cout[(size_t)row * 1024 + col] = v;
      }
  }
}

// ---------------------------------------------------------------------------
// main fused kernel — R8 skeleton (16 waves x 64x64, acc[4][4], reg-dbuf B,
// A f32->reg->bf16->swizzled LDS dbuf) with ONE change: the K-loop barrier is
// a raw s_barrier + lgkmcnt(0) ONLY (no vmcnt drain). __syncthreads()'s
// implicit vmcnt(0) was killing both prefetches every iteration (R8 measured
// 4220cy/iter ~= sum of all pipes). B and A prefetches are VGPR-destination
// loads — no cross-wave visibility requirement — so the barrier only needs
// LDS ordering. Their consumers' compiler-auto vmcnt waits resolve to ops
// issued >= 1 full step earlier => zero stall; steady state keeps A(k+2) +
// B(k+1) in flight across every barrier. Protocol (raw barrier + fences)
// verified green in R6.
// Epilogue: +t_part, exact GELU, LayerNorm (16-wave LDS reduce),
// softmax-weighted K-reduce -> arg_summary. (unchanged, green)
// ---------------------------------------------------------------------------
#define MFMA_STEP(ABSYM, BF) do {                                         \
  bf16x8 af_[4];                                                          \
  _Pragma("unroll")                                                       \
  for (int mf = 0; mf < 4; ++mf)                                          \
    af_[mf] = *(const bf16x8*)((const char*)(ABSYM) + aoff[mf]);          \
  _Pragma("unroll")                                                       \
  for (int nf = 0; nf < 4; ++nf)                                          \
    _Pragma("unroll")                                                     \
    for (int mf = 0; mf < 4; ++mf)                                        \
      acc[mf][nf] = __builtin_amdgcn_mfma_f32_16x16x32_bf16(              \
          af_[mf], (BF)[nf], acc[mf][nf], 0, 0, 0);                       \
} while (0)

// Raw barrier: LDS ordering only; VGPR-dest global loads stay in flight.
#define BARRIER_LG() do {                                                 \
  asm volatile("s_waitcnt lgkmcnt(0)" ::: "memory");                      \
  __builtin_amdgcn_s_barrier();                                           \
  asm volatile("" ::: "memory");                                          \
} while (0)

__global__ __launch_bounds__(1024) void main_kernel(
    const float* __restrict__ routed, const float* __restrict__ delta,
    const float* __restrict__ simrow, const ushort* __restrict__ Bmain,
    const float* __restrict__ tpart, const float* __restrict__ gamma,
    const float* __restrict__ beta, float* __restrict__ out_arg) {
  __shared__ ushort Ab0[2048];          // 4KB A tile [64][32] bf16 (swz)
  __shared__ ushort Ab1[2048];
  __shared__ float ldsW[64];            // softmax weights 4 tokens x 16 k
  __shared__ float lnS[64 * 16], lnQ[64 * 16];

  int tid = threadIdx.x, l = tid & 63, wid = tid >> 6;   // wid 0..15
  int bx = blockIdx.x;                  // tokens bx*4 .. bx*4+3
  int lr = l & 15, lh = l >> 4;

  if (tid < 4) {                        // softmax over K=16 for token bx*4+tid
    int n = bx * 4 + tid;
    float sv[16], mx = -1e30f;
#pragma unroll
    for (int j = 0; j < 16; ++j) { sv[j] = simrow[n * 16 + j]; mx = fmaxf(mx, sv[j]); }
    float s = 0.f;
#pragma unroll
    for (int j = 0; j < 16; ++j) { sv[j] = expf(sv[j] - mx); s += sv[j]; }
    float inv = 1.0f / s;
#pragma unroll
    for (int j = 0; j < 16; ++j) ldsW[tid * 16 + j] = sv[j] * inv;
  }

  // A staging geometry: 1024 threads x 4B of the 4KB tile.
  const int arow = tid >> 4;
  const float* rbase = routed + (size_t)(bx * 64 + arow) * 1024 + (tid & 15) * 2;
  const float* dbase = delta  + (size_t)(bx * 64 + arow) * 1024 + (tid & 15) * 2;
  const unsigned adst = swz((unsigned)tid * 4);

  // A-tile read offsets (loop-invariant, swizzled)
  unsigned aoff[4];
#pragma unroll
  for (int mf = 0; mf < 4; ++mf)
    aoff[mf] = swz((unsigned)(mf * 16 + lr) * 64 + (unsigned)lh * 16);

  // B per-lane pointer: wave wid covers cols wid*64 + nf*16 + lr.
  // packed: wg = wid>>1, chunk = ((wid&1)*4+nf)*64 + l -> 16B/lane coalesced
  const ushort* bptr = Bmain + (size_t)(wid >> 1) * 4096 +
                       (size_t)(wid & 1) * 2048 + (size_t)l * 8;

  // ---- prologue: A(0)->Ab0, A(1)->avA, B(0)->bfA ----
  float2 t0 = *(const float2*)rbase;
  float2 avA = *(const float2*)(rbase + 32);
  float2 avB;
  bf16x8 bfA[4], bfB[4];
#pragma unroll
  for (int nf = 0; nf < 4; ++nf)
    bfA[nf] = *(const bf16x8*)(bptr + nf * 512);
  *(unsigned*)((char*)Ab0 + adst) = pk2(t0.x, t0.y);
  BARRIER_LG();

  f32x4 acc[4][4] = {};
#pragma unroll 1
  for (int kt = 0; kt < 64; kt += 2) {
    // ===== even step: consume Ab0 + bfA =====
    {                                    // A(kt+2) issued, stays in flight
      const float* as_ = (kt + 2 < 32) ? rbase : dbase;
      avB = *(const float2*)(as_ + (size_t)((kt + 2) & 31) * 32);
    }
#pragma unroll
    for (int nf = 0; nf < 4; ++nf)       // B(kt+1) issued, stays in flight
      bfB[nf] = *(const bf16x8*)(bptr + 32768 + nf * 512);
    asm volatile("" ::: "memory");       // pin load issue above compute
    MFMA_STEP(Ab0, bfA);
    *(unsigned*)((char*)Ab1 + adst) = pk2(avA.x, avA.y);   // A(kt+1)->Ab1
    BARRIER_LG();
    // ===== odd step: consume Ab1 + bfB =====
    {                                    // A(kt+3) (benign over-read at end)
      const float* as_ = (kt + 3 < 32) ? rbase : dbase;
      avA = *(const float2*)(as_ + (size_t)((kt + 3) & 31) * 32);
    }
#pragma unroll
    for (int nf = 0; nf < 4; ++nf)       // B(kt+2) (benign over-read at end)
      bfA[nf] = *(const bf16x8*)(bptr + 65536 + nf * 512);
    asm volatile("" ::: "memory");
    MFMA_STEP(Ab1, bfB);
    *(unsigned*)((char*)Ab0 + adst) = pk2(avB.x, avB.y);   // A(kt+2)->Ab0
    BARRIER_LG();
    bptr += 65536;
  }

  // ---- fused epilogue (unchanged, green) ----
  // acc[mf][nf][j]: local row mf*16 + lh*4 + j (= token mf, k = lh*4+j),
  //                 col wid*64 + nf*16 + lr
  const float inv_d = 1.0f / 1024.0f;
  float gam[4], bet[4];
#pragma unroll
  for (int nf = 0; nf < 4; ++nf) {
    int c = wid * 64 + nf * 16 + lr;
    gam[nf] = gamma[c]; bet[nf] = beta[c];
  }
#pragma unroll
  for (int mf = 0; mf < 4; ++mf) {
    int tokrow = bx * 4 + mf;
    float s[4] = {0, 0, 0, 0}, q[4] = {0, 0, 0, 0};
#pragma unroll
    for (int nf = 0; nf < 4; ++nf) {
      float tp = tpart[(size_t)tokrow * 1024 + wid * 64 + nf * 16 + lr];
#pragma unroll
      for (int j = 0; j < 4; ++j) {
        float h = acc[mf][nf][j] + tp;
        float g = 0.5f * h * (1.0f + erff(h * 0.70710678118654752f));
        acc[mf][nf][j] = g;
        s[j] += g; q[j] += g * g;
      }
    }
#pragma unroll
    for (int j = 0; j < 4; ++j) {
#pragma unroll
      for (int d = 1; d <= 8; d <<= 1) {
        s[j] += __shfl_xor(s[j], d, 64);
        q[j] += __shfl_xor(q[j], d, 64);
      }
    }
    if (lr == 0) {
#pragma unroll
      for (int j = 0; j < 4; ++j) {
        int row = mf * 16 + lh * 4 + j;
        lnS[row * 16 + wid] = s[j];
        lnQ[row * 16 + wid] = q[j];
      }
    }
  }
  __syncthreads();
#pragma unroll
  for (int mf = 0; mf < 4; ++mf) {
    float mu[4], rs[4], wk[4];
#pragma unroll
    for (int j = 0; j < 4; ++j) {
      int row = mf * 16 + lh * 4 + j;
      float S = 0.f, Q = 0.f;
#pragma unroll
      for (int w4 = 0; w4 < 4; ++w4) {
        f32x4 vs = *(const f32x4*)&lnS[row * 16 + w4 * 4];
        f32x4 vq = *(const f32x4*)&lnQ[row * 16 + w4 * 4];
        S += vs[0] + vs[1] + vs[2] + vs[3];
        Q += vq[0] + vq[1] + vq[2] + vq[3];
      }
      float m_ = S * inv_d;
      mu[j] = m_;
      rs[j] = rsqrtf(Q * inv_d - m_ * m_ + 1e-5f);
      wk[j] = ldsW[row];
    }
#pragma unroll
    for (int nf = 0; nf < 4; ++nf) {
      float ws = 0.f;
#pragma unroll
      for (int j = 0; j < 4; ++j) {
        float y = (acc[mf][nf][j] - mu[j]) * rs[j] * gam[nf] + bet[nf];
        ws += wk[j] * y;
      }
      ws += __shfl_xor(ws, 16, 64);
      ws += __shfl_xor(ws, 32, 64);
      if (lh == 0)
        out_arg[(size_t)(bx * 4 + mf) * 1024 + wid * 64 + nf * 16 + lr] = ws;
    }
  }
}

// ---------------------------------------------------------------------------
extern "C" void kernel_launch(void* const* d_in, const int* in_sizes, int n_in,
                              void* d_out, int out_size, void* d_ws, size_t ws_size,
                              hipStream_t stream) {
  const float* token  = (const float*)d_in[0];
  const float* routed = (const float*)d_in[1];
  const float* simrow = (const float*)d_in[2];
  const float* delta  = (const float*)d_in[3];
  const float* Wl     = (const float*)d_in[4];
  const float* bl     = (const float*)d_in[5];
  const float* gamma  = (const float*)d_in[6];
  const float* beta   = (const float*)d_in[7];
  const float* Wg     = (const float*)d_in[8];
  const float* bg     = (const float*)d_in[9];

  char* ws = (char*)d_ws;
  ushort* Bmain = (ushort*)(ws);                         // 4 MB
  ushort* Bk1   = (ushort*)(ws + (4u << 20));            // 2 MB
  ushort* Bgate = (ushort*)(ws + (6u << 20));            // 4 MB
  float*  tpart = (float*)(ws + (10u << 20));            // 16 MB

  float* out_arg  = (float*)d_out;
  float* out_gate = out_arg + (size_t)4096 * 1024;

  prep_kernel<<<1280, 256, 0, stream>>>(Wl, Wg, Bmain, Bk1, Bgate);
  gemm_small<32, 32, 0><<<dim3(64, 8), 256, 0, stream>>>(
      token, token, Bk1, bl, tpart);
  main_kernel<<<1024, 1024, 0, stream>>>(
      routed, delta, simrow, Bmain, tpart, gamma, beta, out_arg);
  gemm_small<64, 32, 1><<<dim3(64, 8), 256, 0, stream>>>(
      token, out_arg, Bgate, bg, out_gate);
}

// Round 10
// 532.666 us; speedup vs baseline: 2.7293x; 2.7293x over previous
//
#include <hip/hip_runtime.h>
#include <hip/hip_bf16.h>

// Problem constants: D=1024, N=4096, K=16, M = N*K = 65536, K-dim main = 2048

typedef __attribute__((ext_vector_type(4))) float f32x4;
typedef __attribute__((ext_vector_type(8))) short bf16x8;

__device__ __forceinline__ ushort f2bf(float f) {
  unsigned b = __builtin_bit_cast(unsigned, f);
  b += 0x7FFFu + ((b >> 16) & 1u);   // RNE
  return (ushort)(b >> 16);
}
__device__ __forceinline__ unsigned pk2(float a, float b) {
  return (unsigned)f2bf(a) | ((unsigned)f2bf(b) << 16);
}

// LDS XOR swizzle for the A tile (verified in passing R1/R4/R6-R9 kernels)
__device__ __forceinline__ unsigned swz(unsigned a) {
  return a ^ (((a >> 7) & 3u) << 4);
}

__device__ __forceinline__ bf16x8 cvt8(const float* p) {
  f32x4 a = *(const f32x4*)p;
  f32x4 b = *(const f32x4*)(p + 4);
  bf16x8 r;
  r[0] = (short)f2bf(a[0]); r[1] = (short)f2bf(a[1]);
  r[2] = (short)f2bf(a[2]); r[3] = (short)f2bf(a[3]);
  r[4] = (short)f2bf(b[0]); r[5] = (short)f2bf(b[1]);
  r[6] = (short)f2bf(b[2]); r[7] = (short)f2bf(b[3]);
  return r;
}

// ---------------------------------------------------------------------------
// prep: LDS tile-transpose weight packer (verified green R4-R9).
// mode 0 (bid<512):  Bmain packed layout: flat = kt*32768 + wg*4096 + c*8 + m,
//                    chunk c = nf*64 + lane; value = Wl[1024+kt*32+(lane>>4)*8+m]
//                                                      [wg*128+nf*16+(lane&15)]
// mode 1 (512..768): Bk1 layout [kt][nn][q*8+m] from Wl rows 0..1023
// mode 2 (768..1280): Bgate same layout from Wg rows kt*32 (+ row+1024 summed
//                    when kt>=32)
// ---------------------------------------------------------------------------
__global__ __launch_bounds__(256) void prep_kernel(
    const float* __restrict__ Wl, const float* __restrict__ Wg,
    ushort* __restrict__ Bmain, ushort* __restrict__ Bk1,
    ushort* __restrict__ Bgate) {
  __shared__ float L[32][129];
  int t = threadIdx.x;
  int bid = blockIdx.x;
  const float* src; int row0, mode, kt, wg; ushort* dst;
  if (bid < 512)      { mode = 0; kt = bid >> 3;        wg = bid & 7; src = Wl; row0 = 1024 + kt * 32; dst = Bmain; }
  else if (bid < 768) { mode = 1; kt = (bid - 512) >> 3; wg = (bid - 512) & 7; src = Wl; row0 = kt * 32; dst = Bk1; }
  else                { mode = 2; kt = (bid - 768) >> 3; wg = (bid - 768) & 7; src = Wg; row0 = kt * 32; dst = Bgate; }
  int col0 = wg * 128;
  bool dosum = (mode == 2) && (kt >= 32);
#pragma unroll
  for (int p = 0; p < 4; ++p) {
    int r = p * 8 + (t >> 5), c = (t & 31) * 4;
    const float* sp = src + (size_t)(row0 + r) * 1024 + col0 + c;
    f32x4 v = *(const f32x4*)sp;
    if (dosum) { f32x4 v2 = *(const f32x4*)(sp + (size_t)1024 * 1024); v += v2; }
    L[r][c] = v[0]; L[r][c + 1] = v[1]; L[r][c + 2] = v[2]; L[r][c + 3] = v[3];
  }
  __syncthreads();
  if (mode == 0) {
    for (int c = t; c < 512; c += 256) {
      int nf = c >> 6, lane = c & 63, lr_ = lane & 15, lh_ = lane >> 4;
      bf16x8 o;
#pragma unroll
      for (int m = 0; m < 8; ++m) o[m] = (short)f2bf(L[lh_ * 8 + m][nf * 16 + lr_]);
      *(bf16x8*)(dst + (size_t)kt * 32768 + wg * 4096 + c * 8) = o;
    }
  } else {
    for (int c = t; c < 512; c += 256) {
      int nn = c >> 2, q = c & 3;
      bf16x8 o;
#pragma unroll
      for (int m = 0; m < 8; ++m) o[m] = (short)f2bf(L[q * 8 + m][nn]);
      *(bf16x8*)(dst + (size_t)kt * 32768 + (size_t)(wg * 128 + nn) * 32 + q * 8) = o;
    }
  }
}

// ---------------------------------------------------------------------------
// gemm_small: C = act(A_f32 @ Bpack + bias). 64x128 tile, 4 waves (2x2),
// wave tile 32x64. grid (M/64, 8) = 512 blocks -> 2 blocks/CU. (green)
// ---------------------------------------------------------------------------
template <int NKT, int NSPLIT, int ACT>
__global__ __launch_bounds__(256) void gemm_small(
    const float* __restrict__ A0, const float* __restrict__ A1,
    const ushort* __restrict__ Bp, const float* __restrict__ bias,
    float* __restrict__ Cout) {
  int tid = threadIdx.x, l = tid & 63, wid = tid >> 6;
  int wm = wid & 1, wn = wid >> 1;
  int mbase = blockIdx.x * 64 + wm * 32;
  int nbase = blockIdx.y * 128 + wn * 64;
  int lr = l & 15, lh = l >> 4;
  f32x4 acc[2][4] = {};
#pragma unroll 1
  for (int kt = 0; kt < NKT; ++kt) {
    const float* As = (kt < NSPLIT) ? A0 : A1;
    int ke = ((kt < NSPLIT) ? kt : kt - NSPLIT) * 32 + lh * 8;
    bf16x8 af[2];
#pragma unroll
    for (int mf = 0; mf < 2; ++mf)
      af[mf] = cvt8(As + (size_t)(mbase + mf * 16 + lr) * 1024 + ke);
    bf16x8 bf[4];
#pragma unroll
    for (int nf = 0; nf < 4; ++nf)
      bf[nf] = *(const bf16x8*)(Bp + (size_t)kt * 32768 +
                                (size_t)(nbase + nf * 16 + lr) * 32 + lh * 8);
#pragma unroll
    for (int nf = 0; nf < 4; ++nf)
#pragma unroll
      for (int mf = 0; mf < 2; ++mf)
        acc[mf][nf] = __builtin_amdgcn_mfma_f32_16x16x32_bf16(
            af[mf], bf[nf], acc[mf][nf], 0, 0, 0);
  }
#pragma unroll
  for (int nf = 0; nf < 4; ++nf) {
    int col = nbase + nf * 16 + lr;
    float bs = bias[col];
#pragma unroll
    for (int mf = 0; mf < 2; ++mf)
#pragma unroll
      for (int j = 0; j < 4; ++j) {
        int row = mbase + mf * 16 + lh * 4 + j;
        float v = acc[mf][nf][j] + bs;
        if (ACT == 1) v = 1.0f / (1.0f + expf(-v));
        Cout[(size_t)row * 1024 + col] = v;
      }
  }
}

// ---------------------------------------------------------------------------
// main fused kernel — R9 protocol (raw s_barrier + lgkmcnt(0) only; VGPR-dest
// prefetches may span barriers) with the two spill-causers removed:
//  (1) NO pin fences between load-issue and MFMA (R9's fences forced all
//      prefetched values simultaneously live -> 2.3GB scratch spill; m141
//      lesson: don't pin the scheduler).
//  (2) A-fragment ds_reads use ONE base reg + compile-time +mf*1024 offsets
//      (swz XOR is mf-invariant: mf contributes a multiple of 4 to addr bits
//      7,8), freeing 3 VGPRs in the 64-VGPR non-acc budget.
// Structure otherwise = green R8: 16 waves x 64x64, acc[4][4], reg-dbuf B
// (named bfA/bfB, 2-step unroll), A f32->reg->bf16->swizzled LDS dbuf.
// Epilogue: +t_part, exact GELU, LayerNorm (16-wave LDS reduce),
// softmax-weighted K-reduce -> arg_summary. (unchanged, green)
// ---------------------------------------------------------------------------
#define MFMA_STEP(ABSYM, BF) do {                                         \
  const char* ab_ = (const char*)(ABSYM) + aoff0;                         \
  bf16x8 af_[4];                                                          \
  _Pragma("unroll")                                                       \
  for (int mf = 0; mf < 4; ++mf)                                          \
    af_[mf] = *(const bf16x8*)(ab_ + mf * 1024);                          \
  _Pragma("unroll")                                                       \
  for (int nf = 0; nf < 4; ++nf)                                          \
    _Pragma("unroll")                                                     \
    for (int mf = 0; mf < 4; ++mf)                                        \
      acc[mf][nf] = __builtin_amdgcn_mfma_f32_16x16x32_bf16(              \
          af_[mf], (BF)[nf], acc[mf][nf], 0, 0, 0);                       \
} while (0)

// Raw barrier: LDS ordering only; VGPR-dest global loads stay in flight.
#define BARRIER_LG() do {                                                 \
  asm volatile("s_waitcnt lgkmcnt(0)" ::: "memory");                      \
  __builtin_amdgcn_s_barrier();                                           \
  asm volatile("" ::: "memory");                                          \
} while (0)

__global__ __launch_bounds__(1024) void main_kernel(
    const float* __restrict__ routed, const float* __restrict__ delta,
    const float* __restrict__ simrow, const ushort* __restrict__ Bmain,
    const float* __restrict__ tpart, const float* __restrict__ gamma,
    const float* __restrict__ beta, float* __restrict__ out_arg) {
  __shared__ ushort Ab0[2048];          // 4KB A tile [64][32] bf16 (swz)
  __shared__ ushort Ab1[2048];
  __shared__ float ldsW[64];            // softmax weights 4 tokens x 16 k
  __shared__ float lnS[64 * 16], lnQ[64 * 16];

  int tid = threadIdx.x, l = tid & 63, wid = tid >> 6;   // wid 0..15
  int bx = blockIdx.x;                  // tokens bx*4 .. bx*4+3
  int lr = l & 15, lh = l >> 4;

  if (tid < 4) {                        // softmax over K=16 for token bx*4+tid
    int n = bx * 4 + tid;
    float sv[16], mx = -1e30f;
#pragma unroll
    for (int j = 0; j < 16; ++j) { sv[j] = simrow[n * 16 + j]; mx = fmaxf(mx, sv[j]); }
    float s = 0.f;
#pragma unroll
    for (int j = 0; j < 16; ++j) { sv[j] = expf(sv[j] - mx); s += sv[j]; }
    float inv = 1.0f / s;
#pragma unroll
    for (int j = 0; j < 16; ++j) ldsW[tid * 16 + j] = sv[j] * inv;
  }

  // A staging geometry: 1024 threads x 4B of the 4KB tile.
  const int arow = tid >> 4;
  const float* rbase = routed + (size_t)(bx * 64 + arow) * 1024 + (tid & 15) * 2;
  const float* dbase = delta  + (size_t)(bx * 64 + arow) * 1024 + (tid & 15) * 2;
  const unsigned adst = swz((unsigned)tid * 4);

  // A-tile read base offset (swz XOR independent of mf; +mf*1024 folds to imm)
  const unsigned aoff0 = swz((unsigned)lr * 64 + (unsigned)lh * 16);

  // B per-lane pointer: wave wid covers cols wid*64 + nf*16 + lr.
  // packed: wg = wid>>1, chunk = ((wid&1)*4+nf)*64 + l -> 16B/lane coalesced
  const ushort* bptr = Bmain + (size_t)(wid >> 1) * 4096 +
                       (size_t)(wid & 1) * 2048 + (size_t)l * 8;

  // ---- prologue: A(0)->Ab0, A(1)->avA, B(0)->bfA ----
  float2 t0 = *(const float2*)rbase;
  float2 avA = *(const float2*)(rbase + 32);
  float2 avB;
  bf16x8 bfA[4], bfB[4];
#pragma unroll
  for (int nf = 0; nf < 4; ++nf)
    bfA[nf] = *(const bf16x8*)(bptr + nf * 512);
  *(unsigned*)((char*)Ab0 + adst) = pk2(t0.x, t0.y);
  BARRIER_LG();

  f32x4 acc[4][4] = {};
#pragma unroll 1
  for (int kt = 0; kt < 64; kt += 2) {
    // ===== even step: consume Ab0 + bfA =====
    {                                    // A(kt+2) issued, stays in flight
      const float* as_ = (kt + 2 < 32) ? rbase : dbase;
      avB = *(const float2*)(as_ + (size_t)((kt + 2) & 31) * 32);
    }
#pragma unroll
    for (int nf = 0; nf < 4; ++nf)       // B(kt+1) issued, stays in flight
      bfB[nf] = *(const bf16x8*)(bptr + 32768 + nf * 512);
    MFMA_STEP(Ab0, bfA);
    *(unsigned*)((char*)Ab1 + adst) = pk2(avA.x, avA.y);   // A(kt+1)->Ab1
    BARRIER_LG();
    // ===== odd step: consume Ab1 + bfB =====
    {                                    // A(kt+3) (benign over-read at end)
      const float* as_ = (kt + 3 < 32) ? rbase : dbase;
      avA = *(const float2*)(as_ + (size_t)((kt + 3) & 31) * 32);
    }
#pragma unroll
    for (int nf = 0; nf < 4; ++nf)       // B(kt+2) (benign over-read at end)
      bfA[nf] = *(const bf16x8*)(bptr + 65536 + nf * 512);
    MFMA_STEP(Ab1, bfB);
    *(unsigned*)((char*)Ab0 + adst) = pk2(avB.x, avB.y);   // A(kt+2)->Ab0
    BARRIER_LG();
    bptr += 65536;
  }

  // ---- fused epilogue (unchanged, green) ----
  // acc[mf][nf][j]: local row mf*16 + lh*4 + j (= token mf, k = lh*4+j),
  //                 col wid*64 + nf*16 + lr
  const float inv_d = 1.0f / 1024.0f;
  float gam[4], bet[4];
#pragma unroll
  for (int nf = 0; nf < 4; ++nf) {
    int c = wid * 64 + nf * 16 + lr;
    gam[nf] = gamma[c]; bet[nf] = beta[c];
  }
#pragma unroll
  for (int mf = 0; mf < 4; ++mf) {
    int tokrow = bx * 4 + mf;
    float s[4] = {0, 0, 0, 0}, q[4] = {0, 0, 0, 0};
#pragma unroll
    for (int nf = 0; nf < 4; ++nf) {
      float tp = tpart[(size_t)tokrow * 1024 + wid * 64 + nf * 16 + lr];
#pragma unroll
      for (int j = 0; j < 4; ++j) {
        float h = acc[mf][nf][j] + tp;
        float g = 0.5f * h * (1.0f + erff(h * 0.70710678118654752f));
        acc[mf][nf][j] = g;
        s[j] += g; q[j] += g * g;
      }
    }
#pragma unroll
    for (int j = 0; j < 4; ++j) {
#pragma unroll
      for (int d = 1; d <= 8; d <<= 1) {
        s[j] += __shfl_xor(s[j], d, 64);
        q[j] += __shfl_xor(q[j], d, 64);
      }
    }
    if (lr == 0) {
#pragma unroll
      for (int j = 0; j < 4; ++j) {
        int row = mf * 16 + lh * 4 + j;
        lnS[row * 16 + wid] = s[j];
        lnQ[row * 16 + wid] = q[j];
      }
    }
  }
  __syncthreads();
#pragma unroll
  for (int mf = 0; mf < 4; ++mf) {
    float mu[4], rs[4], wk[4];
#pragma unroll
    for (int j = 0; j < 4; ++j) {
      int row = mf * 16 + lh * 4 + j;
      float S = 0.f, Q = 0.f;
#pragma unroll
      for (int w4 = 0; w4 < 4; ++w4) {
        f32x4 vs = *(const f32x4*)&lnS[row * 16 + w4 * 4];
        f32x4 vq = *(const f32x4*)&lnQ[row * 16 + w4 * 4];
        S += vs[0] + vs[1] + vs[2] + vs[3];
        Q += vq[0] + vq[1] + vq[2] + vq[3];
      }
      float m_ = S * inv_d;
      mu[j] = m_;
      rs[j] = rsqrtf(Q * inv_d - m_ * m_ + 1e-5f);
      wk[j] = ldsW[row];
    }
#pragma unroll
    for (int nf = 0; nf < 4; ++nf) {
      float ws = 0.f;
#pragma unroll
      for (int j = 0; j < 4; ++j) {
        float y = (acc[mf][nf][j] - mu[j]) * rs[j] * gam[nf] + bet[nf];
        ws += wk[j] * y;
      }
      ws += __shfl_xor(ws, 16, 64);
      ws += __shfl_xor(ws, 32, 64);
      if (lh == 0)
        out_arg[(size_t)(bx * 4 + mf) * 1024 + wid * 64 + nf * 16 + lr] = ws;
    }
  }
}

// ---------------------------------------------------------------------------
extern "C" void kernel_launch(void* const* d_in, const int* in_sizes, int n_in,
                              void* d_out, int out_size, void* d_ws, size_t ws_size,
                              hipStream_t stream) {
  const float* token  = (const float*)d_in[0];
  const float* routed = (const float*)d_in[1];
  const float* simrow = (const float*)d_in[2];
  const float* delta  = (const float*)d_in[3];
  const float* Wl     = (const float*)d_in[4];
  const float* bl     = (const float*)d_in[5];
  const float* gamma  = (const float*)d_in[6];
  const float* beta   = (const float*)d_in[7];
  const float* Wg     = (const float*)d_in[8];
  const float* bg     = (const float*)d_in[9];

  char* ws = (char*)d_ws;
  ushort* Bmain = (ushort*)(ws);                         // 4 MB
  ushort* Bk1   = (ushort*)(ws + (4u << 20));            // 2 MB
  ushort* Bgate = (ushort*)(ws + (6u << 20));            // 4 MB
  float*  tpart = (float*)(ws + (10u << 20));            // 16 MB

  float* out_arg  = (float*)d_out;
  float* out_gate = out_arg + (size_t)4096 * 1024;

  prep_kernel<<<1280, 256, 0, stream>>>(Wl, Wg, Bmain, Bk1, Bgate);
  gemm_small<32, 32, 0><<<dim3(64, 8), 256, 0, stream>>>(
      token, token, Bk1, bl, tpart);
  main_kernel<<<1024, 1024, 0, stream>>>(
      routed, delta, simrow, Bmain, tpart, gamma, beta, out_arg);
  gemm_small<64, 32, 1><<<dim3(64, 8), 256, 0, stream>>>(
      token, out_arg, Bgate, bg, out_gate);
}